// Round 4
// baseline (364.538 us; speedup 1.0000x reference)
//
#include <hip/hip_runtime.h>
#include <hip/hip_fp16.h>

typedef __attribute__((ext_vector_type(8))) _Float16 f16x8;
typedef __attribute__((ext_vector_type(4))) _Float16 f16x4;
typedef __attribute__((ext_vector_type(8))) unsigned short u16x8;
typedef __attribute__((ext_vector_type(4))) float f32x4;

constexpr int NT = 256;
constexpr int TILE_SHORTS = 4096;   // 64 rows x 64 fp16 = 8KB tile image

// phys 16B-chunk swizzle: row r, logical chunk c (0..7) -> short offset
__device__ __forceinline__ int swzoff(int row, int c) {
    return row * 64 + ((c ^ (row & 7)) << 3);
}
__device__ __forceinline__ unsigned short f2h_u(float x) {
    return __half_as_ushort(__float2half(x));
}

// ===== single launch: per-block tile convert -> release flag -> attn ======
// Block (bh,qt) converts K/V tile (bh, tile=qt) to fp16 swizzled images
// (bijective over all 512 tiles, XCD-pinned), publishes it with a
// device-scope release flag, then runs the R0-measured-best LDS attn
// pipeline, acquire-polling each tile's flag before its prefetch.
// Co-residency of all 512 blocks (2/CU) was proven by the R2 coop launch,
// so the spin cannot deadlock.
__global__ __launch_bounds__(NT, 2) void fused_attn(
    const float* __restrict__ Qg,
    const float* __restrict__ Kg, const float* __restrict__ Vg,
    unsigned short* __restrict__ Kw, unsigned short* __restrict__ Vw,
    int* __restrict__ flags, float* __restrict__ Og)
{
    __shared__ __align__(16) unsigned short lds[4 * TILE_SHORTS];  // 32 KiB
    const int tid  = threadIdx.x;
    const int lane = tid & 63;
    const int wave = tid >> 6;
    const int a    = lane & 15;
    const int quad = lane >> 4;
    const int m0   = wave * 16;

    // XCD-pinned heavy/light mapping: per XCD, CU c gets qt=31-c (bh even)
    // and qt=c (bh odd) -> 33 tile-iters per CU. Light blocks convert the
    // early-needed tiles.
    const int bid = (int)blockIdx.x;
    const int xcd = bid & 7;
    const int y   = bid >> 3;
    const int yy  = y & 31;
    const int bh  = xcd * 2 + (y >= 32);
    const int qt  = (y < 32) ? (31 - yy) : yy;
    const int b = bh >> 3, h = bh & 7;
    const int q0 = qt * 64;

    // ---- Q B-frags early: HBM latency hides under the convert phase ----
    f16x8 bQ[2];
    {
        const size_t qrowbase = (((size_t)b * 2048 + q0 + m0 + a) * 8 + h) * 64;
        #pragma unroll
        for (int ks = 0; ks < 2; ++ks) {
            const float* src = &Qg[qrowbase + ks * 32 + quad * 8];
            float4 x = *(const float4*)src, y2 = *(const float4*)(src + 4);
            u16x8 o;
            o[0] = f2h_u(x.x); o[1] = f2h_u(x.y); o[2] = f2h_u(x.z); o[3] = f2h_u(x.w);
            o[4] = f2h_u(y2.x); o[5] = f2h_u(y2.y); o[6] = f2h_u(y2.z); o[7] = f2h_u(y2.w);
            bQ[ks] = __builtin_bit_cast(f16x8, o);
        }
    }

    // ================= phase 1: convert tile (bh, qt) =================
    {
        float* Vl = (float*)lds;          // 64*68 f32 = 17.4 KB, aliased
        const int tile = qt;
        const size_t gbase = (((size_t)b * 2048 + tile * 64) * 8 + h) * 64;

        // stage V tile f32 into LDS (coalesced)
        #pragma unroll
        for (int j = 0; j < 4; ++j) {
            int id = j * 256 + tid, row = id >> 4, c4 = id & 15;
            *(float4*)&Vl[row * 68 + c4 * 4] =
                *(const float4*)&Vg[gbase + (size_t)row * 512 + c4 * 4];
        }

        // K image: row-major fp16, 16B chunks XOR-swizzled (no LDS dep)
        unsigned short* Ko = Kw + (size_t)(bh * 32 + tile) * TILE_SHORTS;
        #pragma unroll
        for (int j = 0; j < 2; ++j) {
            int id = j * 256 + tid, row = id >> 3, c = id & 7;
            const float* src = &Kg[gbase + (size_t)row * 512 + c * 8];
            float4 x = *(const float4*)src, y2 = *(const float4*)(src + 4);
            u16x8 o;
            o[0] = f2h_u(x.x); o[1] = f2h_u(x.y); o[2] = f2h_u(x.z); o[3] = f2h_u(x.w);
            o[4] = f2h_u(y2.x); o[5] = f2h_u(y2.y); o[6] = f2h_u(y2.z); o[7] = f2h_u(y2.w);
            *(u16x8*)&Ko[swzoff(row, c)] = o;
        }
        __syncthreads();

        // V^T image, k-permuted so one b128 = the 4 B-frags of 16x16x16 PV:
        // store at k' = quad*16 + c*4 + i the element k = c*16 + quad*4 + i
        unsigned short* Vo = Vw + (size_t)(bh * 32 + tile) * TILE_SHORTS;
        #pragma unroll
        for (int j = 0; j < 2; ++j) {
            int id = j * 256 + tid, vrow = id >> 3, g = id & 7;
            u16x8 o;
            #pragma unroll
            for (int jj = 0; jj < 8; ++jj) {
                int kk = ((g & 1) * 2 + (jj >> 2)) * 16 + (g >> 1) * 4 + (jj & 3);
                o[jj] = f2h_u(Vl[kk * 68 + vrow]);
            }
            *(u16x8*)&Vo[swzoff(vrow, g)] = o;
        }
    }

    // all this block's image stores issued; make them visible, then publish
    __syncthreads();               // also frees Vl for LDS reuse below
    if (tid == 0) {
        __threadfence();           // device-scope: drain + order the stores
        __hip_atomic_store(&flags[bh * 32 + qt], 1,
                           __ATOMIC_RELEASE, __HIP_MEMORY_SCOPE_AGENT);
    }

    // ================= phase 2: attention (R0 structure + flag polls) ======
    unsigned short* const Kb = lds;                    // 2 buffers
    unsigned short* const Vb = lds + 2 * TILE_SHORTS;  // 2 buffers

    const unsigned short* Ktiles = Kw + (size_t)bh * 32 * TILE_SHORTS;
    const unsigned short* Vtiles = Vw + (size_t)bh * 32 * TILE_SHORTS;

    auto waittile = [&](int t) {
        // acquire-poll; producer is same-XCD. One-time per tile.
        while (__hip_atomic_load(&flags[bh * 32 + t],
                                 __ATOMIC_ACQUIRE, __HIP_MEMORY_SCOPE_AGENT) == 0)
            __builtin_amdgcn_s_sleep(1);
    };

    // register-staged tile prefetch (byte-copy of pre-swizzled images)
    u16x8 rK[2], rV[2];
    auto gload = [&](int kt) {
        const u16x8* kg = (const u16x8*)(Ktiles + (size_t)kt * TILE_SHORTS);
        const u16x8* vg = (const u16x8*)(Vtiles + (size_t)kt * TILE_SHORTS);
        rK[0] = kg[tid * 2]; rK[1] = kg[tid * 2 + 1];
        rV[0] = vg[tid * 2]; rV[1] = vg[tid * 2 + 1];
    };
    waittile(0);
    gload(0);

    f32x4 oacc[4];
    #pragma unroll
    for (int n = 0; n < 4; ++n) oacc[n] = (f32x4){0.f, 0.f, 0.f, 0.f};
    float den_l = 0.f;

    union U8 { u16x8 u; f16x4 q[2]; f16x8 f; };

    for (int kt = 0; kt <= qt; ++kt) {
        const int buf = kt & 1;
        u16x8* kd = (u16x8*)(Kb + buf * TILE_SHORTS);
        u16x8* vd = (u16x8*)(Vb + buf * TILE_SHORTS);
        kd[tid * 2] = rK[0]; kd[tid * 2 + 1] = rK[1];
        vd[tid * 2] = rV[0]; vd[tid * 2 + 1] = rV[1];
        __syncthreads();   // buf complete; WAR hazard is 2 barriers back
        if (kt < qt) {
            waittile(kt + 1);          // one-time acquire per tile
            gload(kt + 1);             // drains during this tile's compute
        }

        const unsigned short* Kc = Kb + buf * TILE_SHORTS;
        const unsigned short* Vc = Vb + buf * TILE_SHORTS;

        // ---- S^T = K·Q^T per 16-row k-strip: C-layout == A-layout of S ----
        f32x4 sacc[4];
        #pragma unroll
        for (int s = 0; s < 4; ++s) sacc[s] = (f32x4){0.f, 0.f, 0.f, 0.f};
        #pragma unroll
        for (int s = 0; s < 4; ++s) {
            #pragma unroll
            for (int ks = 0; ks < 2; ++ks) {
                U8 ak; ak.u = *(const u16x8*)&Kc[swzoff(s * 16 + a, ks * 4 + quad)];
                sacc[s] = __builtin_amdgcn_mfma_f32_16x16x32_f16(ak.f, bQ[ks], sacc[s], 0, 0, 0);
            }
        }

        // ---- square, mask (diag), den, convert in-register ----
        const bool diag = (kt == qt);
        f16x4 aS[4];
        #pragma unroll
        for (int s = 0; s < 4; ++s) {
            float p[4];
            #pragma unroll
            for (int r = 0; r < 4; ++r) {
                float d0 = sacc[s][r];
                float v = d0 * d0;
                if (diag && (s * 16 + quad * 4 + r) > (m0 + a)) v = 0.f;
                p[r] = v;
            }
            den_l += (p[0] + p[1]) + (p[2] + p[3]);
            aS[s] = (f16x4){(_Float16)p[0], (_Float16)p[1], (_Float16)p[2], (_Float16)p[3]};
        }

        // ---- PV: O += S·V via 16x16x16, S^T C-regs feed A directly ----
        #pragma unroll
        for (int n = 0; n < 4; ++n) {
            U8 va, vb;
            va.u = *(const u16x8*)&Vc[swzoff(n * 16 + a, quad * 2)];
            vb.u = *(const u16x8*)&Vc[swzoff(n * 16 + a, quad * 2 + 1)];
            oacc[n] = __builtin_amdgcn_mfma_f32_16x16x16f16(aS[0], va.q[0], oacc[n], 0, 0, 0);
            oacc[n] = __builtin_amdgcn_mfma_f32_16x16x16f16(aS[1], va.q[1], oacc[n], 0, 0, 0);
            oacc[n] = __builtin_amdgcn_mfma_f32_16x16x16f16(aS[2], vb.q[0], oacc[n], 0, 0, 0);
            oacc[n] = __builtin_amdgcn_mfma_f32_16x16x16f16(aS[3], vb.q[1], oacc[n], 0, 0, 0);
        }
    }

    // ---- den: reduce across quads (same q=a), then gather per output row ----
    den_l += __shfl_xor(den_l, 16);
    den_l += __shfl_xor(den_l, 32);

    float invz[4];
    #pragma unroll
    for (int r = 0; r < 4; ++r) {
        float dq = __shfl(den_l, quad * 4 + r);   // lane holding a == quad*4+r
        invz[r] = 1.0f / (dq + 1e-5f);
    }

    #pragma unroll
    for (int n = 0; n < 4; ++n) {
        #pragma unroll
        for (int r = 0; r < 4; ++r) {
            int t = q0 + m0 + quad * 4 + r;
            int v = n * 16 + a;
            Og[(((size_t)b * 2048 + t) * 8 + h) * 64 + v] = oacc[n][r] * invz[r];
        }
    }
}

extern "C" void kernel_launch(void* const* d_in, const int* in_sizes, int n_in,
                              void* d_out, int out_size, void* d_ws, size_t ws_size,
                              hipStream_t stream) {
    const float* Q = (const float*)d_in[0];
    const float* K = (const float*)d_in[1];
    const float* V = (const float*)d_in[2];
    float* O = (float*)d_out;
    unsigned short* Kw = (unsigned short*)d_ws;                 // 4 MB
    unsigned short* Vw = Kw + (size_t)16 * 32 * TILE_SHORTS;    // 4 MB
    int* flags = (int*)(Vw + (size_t)16 * 32 * TILE_SHORTS);    // 2 KB

    hipMemsetAsync(flags, 0, 512 * sizeof(int), stream);        // ws is poisoned
    fused_attn<<<dim3(512), NT, 0, stream>>>(Q, K, V, Kw, Vw, flags, O);
}

// Round 6
// 108.529 us; speedup vs baseline: 3.3589x; 3.3589x over previous
//
#include <hip/hip_runtime.h>
#include <hip/hip_fp16.h>

typedef __attribute__((ext_vector_type(8))) _Float16 f16x8;
typedef __attribute__((ext_vector_type(4))) _Float16 f16x4;
typedef __attribute__((ext_vector_type(8))) unsigned short u16x8;
typedef __attribute__((ext_vector_type(4))) float f32x4;

constexpr int NT = 256;
constexpr int TILE_SHORTS = 4096;   // 64 rows x 64 fp16 = 8KB tile image

// phys 16B-chunk swizzle: row r, logical chunk c (0..7) -> short offset
__device__ __forceinline__ int swzoff(int row, int c) {
    return row * 64 + ((c ^ (row & 7)) << 3);
}
__device__ __forceinline__ unsigned short f2h_u(float x) {
    return __half_as_ushort(__float2half(x));
}

// ============ pre-pass: f32 -> fp16 swizzled tile images in ws ============
// (R0-exact version)
__global__ __launch_bounds__(256, 4) void prepass(
    const float* __restrict__ Kg, const float* __restrict__ Vg,
    unsigned short* __restrict__ Kw, unsigned short* __restrict__ Vw)
{
    __shared__ __align__(16) float Vl[64 * 68];
    const int tile = blockIdx.x;      // 0..31
    const int bh   = blockIdx.y;      // 0..15
    const int b = bh >> 3, h = bh & 7;
    const int tid = threadIdx.x;
    const size_t gbase = (((size_t)b * 2048 + tile * 64) * 8 + h) * 64;

    // stage V tile f32 into LDS (coalesced)
    #pragma unroll
    for (int j = 0; j < 4; ++j) {
        int id = j * 256 + tid, row = id >> 4, c4 = id & 15;
        *(float4*)&Vl[row * 68 + c4 * 4] =
            *(const float4*)&Vg[gbase + (size_t)row * 512 + c4 * 4];
    }

    // K image: row-major fp16, 16B chunks XOR-swizzled
    unsigned short* Ko = Kw + (size_t)(bh * 32 + tile) * TILE_SHORTS;
    #pragma unroll
    for (int j = 0; j < 2; ++j) {
        int id = j * 256 + tid, row = id >> 3, c = id & 7;
        const float* src = &Kg[gbase + (size_t)row * 512 + c * 8];
        float4 x = *(const float4*)src, y = *(const float4*)(src + 4);
        u16x8 o;
        o[0] = f2h_u(x.x); o[1] = f2h_u(x.y); o[2] = f2h_u(x.z); o[3] = f2h_u(x.w);
        o[4] = f2h_u(y.x); o[5] = f2h_u(y.y); o[6] = f2h_u(y.z); o[7] = f2h_u(y.w);
        *(u16x8*)&Ko[swzoff(row, c)] = o;
    }
    __syncthreads();

    // V^T image, k-permuted so one b128 = the 4 B-frags of 16x16x16 PV:
    // store at k' = quad*16 + c*4 + i the element k = c*16 + quad*4 + i
    unsigned short* Vo = Vw + (size_t)(bh * 32 + tile) * TILE_SHORTS;
    #pragma unroll
    for (int j = 0; j < 2; ++j) {
        int id = j * 256 + tid, vrow = id >> 3, g = id & 7;
        u16x8 o;
        #pragma unroll
        for (int jj = 0; jj < 8; ++jj) {
            int kk = ((g & 1) * 2 + (jj >> 2)) * 16 + (g >> 1) * 4 + (jj & 3);
            o[jj] = f2h_u(Vl[kk * 68 + vrow]);
        }
        *(u16x8*)&Vo[swzoff(vrow, g)] = o;
    }
}

// ============ main kernel: R0 pipeline + parity-split waves ============
// Wave w = (qhalf=w&1, par=w>>1) owns 32 q-rows (two 16-row m-blocks) and
// computes only tiles with kt&1==par. Each LDS K/V fragment read feeds TWO
// MFMAs -> LDS read traffic per block-iter drops 64KB->32KB. Partial
// oacc/den of the two parities are combined once at the end via LDS.
__global__ __launch_bounds__(NT, 2) void attn_pow2_f16(
    const float* __restrict__ Qg,
    const unsigned short* __restrict__ Kw, const unsigned short* __restrict__ Vw,
    float* __restrict__ Og)
{
    __shared__ __align__(16) unsigned short lds[4 * TILE_SHORTS];  // 32 KiB
    unsigned short* const Kb = lds;                    // 2 buffers
    unsigned short* const Vb = lds + 2 * TILE_SHORTS;  // 2 buffers
    const int tid   = threadIdx.x;
    const int lane  = tid & 63;
    const int wave  = tid >> 6;
    const int a     = lane & 15;
    const int quad  = lane >> 4;
    const int qhalf = wave & 1;     // which 32 q-rows
    const int par   = wave >> 1;    // which tile parity

    // heavy+light pairing swizzle (R0-exact, bijection over 512 blocks)
    int r0 = (int)blockIdx.x;
    int wr = (r0 < 256) ? r0 : (767 - r0);
    const int qt = 31 - (wr >> 4);
    const int bh = wr & 15;
    const int b = bh >> 3, h = bh & 7;
    const int q0 = qt * 64;

    // ---- Q B-frags for both m-blocks: B[n=q=a][k=d=ks*32+quad*8+j] ----
    f16x8 bQ[2][2];   // [mi][ks]
    #pragma unroll
    for (int mi = 0; mi < 2; ++mi) {
        const int mb = qhalf * 32 + mi * 16;
        const size_t qrowbase = (((size_t)b * 2048 + q0 + mb + a) * 8 + h) * 64;
        #pragma unroll
        for (int ks = 0; ks < 2; ++ks) {
            const float* src = &Qg[qrowbase + ks * 32 + quad * 8];
            float4 x = *(const float4*)src, y = *(const float4*)(src + 4);
            u16x8 o;
            o[0] = f2h_u(x.x); o[1] = f2h_u(x.y); o[2] = f2h_u(x.z); o[3] = f2h_u(x.w);
            o[4] = f2h_u(y.x); o[5] = f2h_u(y.y); o[6] = f2h_u(y.z); o[7] = f2h_u(y.w);
            bQ[mi][ks] = __builtin_bit_cast(f16x8, o);
        }
    }

    const unsigned short* Ktiles = Kw + (size_t)bh * 32 * TILE_SHORTS;
    const unsigned short* Vtiles = Vw + (size_t)bh * 32 * TILE_SHORTS;

    // register-staged tile prefetch (byte-copy of pre-swizzled images)
    u16x8 rK[2], rV[2];
    auto gload = [&](int kt) {
        const u16x8* kg = (const u16x8*)(Ktiles + (size_t)kt * TILE_SHORTS);
        const u16x8* vg = (const u16x8*)(Vtiles + (size_t)kt * TILE_SHORTS);
        rK[0] = kg[tid * 2]; rK[1] = kg[tid * 2 + 1];
        rV[0] = vg[tid * 2]; rV[1] = vg[tid * 2 + 1];
    };
    gload(0);

    f32x4 oacc[2][4];   // [mi][n]
    #pragma unroll
    for (int mi = 0; mi < 2; ++mi)
        #pragma unroll
        for (int n = 0; n < 4; ++n) oacc[mi][n] = (f32x4){0.f, 0.f, 0.f, 0.f};
    float den_l[2] = {0.f, 0.f};

    union U8 { u16x8 u; f16x4 q[2]; f16x8 f; };

    for (int kt = 0; kt <= qt; ++kt) {
        const int buf = kt & 1;
        u16x8* kd = (u16x8*)(Kb + buf * TILE_SHORTS);
        u16x8* vd = (u16x8*)(Vb + buf * TILE_SHORTS);
        kd[tid * 2] = rK[0]; kd[tid * 2 + 1] = rK[1];
        vd[tid * 2] = rV[0]; vd[tid * 2 + 1] = rV[1];
        __syncthreads();   // buf complete; WAR hazard is 2 barriers back
        if (kt < qt) gload(kt + 1);   // drains during this tile's compute

        if ((kt & 1) == par) {
            const unsigned short* Kc = Kb + buf * TILE_SHORTS;
            const unsigned short* Vc = Vb + buf * TILE_SHORTS;
            const bool diag = (kt == qt);

            // ---- S^T = K·Q^T per 16-row k-strip, both m-blocks share ak ----
            f32x4 sacc[2][4];
            #pragma unroll
            for (int mi = 0; mi < 2; ++mi)
                #pragma unroll
                for (int s = 0; s < 4; ++s) sacc[mi][s] = (f32x4){0.f, 0.f, 0.f, 0.f};
            #pragma unroll
            for (int s = 0; s < 4; ++s) {
                #pragma unroll
                for (int ks = 0; ks < 2; ++ks) {
                    U8 ak; ak.u = *(const u16x8*)&Kc[swzoff(s * 16 + a, ks * 4 + quad)];
                    sacc[0][s] = __builtin_amdgcn_mfma_f32_16x16x32_f16(ak.f, bQ[0][ks], sacc[0][s], 0, 0, 0);
                    sacc[1][s] = __builtin_amdgcn_mfma_f32_16x16x32_f16(ak.f, bQ[1][ks], sacc[1][s], 0, 0, 0);
                }
            }

            // ---- square, mask (diag), den, convert in-register ----
            f16x4 aS[2][4];
            #pragma unroll
            for (int mi = 0; mi < 2; ++mi) {
                const int mb = qhalf * 32 + mi * 16;
                #pragma unroll
                for (int s = 0; s < 4; ++s) {
                    float p[4];
                    #pragma unroll
                    for (int r = 0; r < 4; ++r) {
                        float d0 = sacc[mi][s][r];
                        float v = d0 * d0;
                        if (diag && (s * 16 + quad * 4 + r) > (mb + a)) v = 0.f;
                        p[r] = v;
                    }
                    den_l[mi] += (p[0] + p[1]) + (p[2] + p[3]);
                    aS[mi][s] = (f16x4){(_Float16)p[0], (_Float16)p[1],
                                        (_Float16)p[2], (_Float16)p[3]};
                }
            }

            // ---- PV: O += S·V, va/vb shared across both m-blocks ----
            #pragma unroll
            for (int n = 0; n < 4; ++n) {
                U8 va, vb;
                va.u = *(const u16x8*)&Vc[swzoff(n * 16 + a, quad * 2)];
                vb.u = *(const u16x8*)&Vc[swzoff(n * 16 + a, quad * 2 + 1)];
                #pragma unroll
                for (int mi = 0; mi < 2; ++mi) {
                    oacc[mi][n] = __builtin_amdgcn_mfma_f32_16x16x16f16(aS[mi][0], va.q[0], oacc[mi][n], 0, 0, 0);
                    oacc[mi][n] = __builtin_amdgcn_mfma_f32_16x16x16f16(aS[mi][1], va.q[1], oacc[mi][n], 0, 0, 0);
                    oacc[mi][n] = __builtin_amdgcn_mfma_f32_16x16x16f16(aS[mi][2], vb.q[0], oacc[mi][n], 0, 0, 0);
                    oacc[mi][n] = __builtin_amdgcn_mfma_f32_16x16x16f16(aS[mi][3], vb.q[1], oacc[mi][n], 0, 0, 0);
                }
            }
        }
    }

    // ---- combine the two parities via LDS (K/V buffers are dead now) ----
    __syncthreads();                               // all loop reads done
    f32x4* xo = (f32x4*)lds;                       // 16 KB: [(n*2+mi)*2+qhalf][lane]
    float*  xd = (float*)((char*)lds + 16384);     // 1 KB: [(qhalf*2+mi)][lane]
    if (par == 1) {
        #pragma unroll
        for (int n = 0; n < 4; ++n)
            #pragma unroll
            for (int mi = 0; mi < 2; ++mi)
                xo[(((n * 2 + mi) * 2) + qhalf) * 64 + lane] = oacc[mi][n];
        xd[(qhalf * 2 + 0) * 64 + lane] = den_l[0];
        xd[(qhalf * 2 + 1) * 64 + lane] = den_l[1];
    }
    __syncthreads();
    if (par == 0) {
        #pragma unroll
        for (int n = 0; n < 4; ++n)
            #pragma unroll
            for (int mi = 0; mi < 2; ++mi)
                oacc[mi][n] += xo[(((n * 2 + mi) * 2) + qhalf) * 64 + lane];
        den_l[0] += xd[(qhalf * 2 + 0) * 64 + lane];
        den_l[1] += xd[(qhalf * 2 + 1) * 64 + lane];

        // den: reduce across quads (same q=a), then gather per output row
        #pragma unroll
        for (int mi = 0; mi < 2; ++mi) {
            den_l[mi] += __shfl_xor(den_l[mi], 16);
            den_l[mi] += __shfl_xor(den_l[mi], 32);
        }

        #pragma unroll
        for (int mi = 0; mi < 2; ++mi) {
            float invz[4];
            #pragma unroll
            for (int r = 0; r < 4; ++r) {
                float dq = __shfl(den_l[mi], quad * 4 + r);
                invz[r] = 1.0f / (dq + 1e-5f);
            }
            const int mb = qhalf * 32 + mi * 16;
            #pragma unroll
            for (int n = 0; n < 4; ++n) {
                #pragma unroll
                for (int r = 0; r < 4; ++r) {
                    int t = q0 + mb + quad * 4 + r;
                    int v = n * 16 + a;
                    Og[(((size_t)b * 2048 + t) * 8 + h) * 64 + v] = oacc[mi][n][r] * invz[r];
                }
            }
        }
    }
}

extern "C" void kernel_launch(void* const* d_in, const int* in_sizes, int n_in,
                              void* d_out, int out_size, void* d_ws, size_t ws_size,
                              hipStream_t stream) {
    const float* Q = (const float*)d_in[0];
    const float* K = (const float*)d_in[1];
    const float* V = (const float*)d_in[2];
    float* O = (float*)d_out;
    unsigned short* Kw = (unsigned short*)d_ws;                 // 4 MB
    unsigned short* Vw = Kw + (size_t)16 * 32 * TILE_SHORTS;    // 4 MB

    prepass<<<dim3(32, 16), 256, 0, stream>>>(K, V, Kw, Vw);
    attn_pow2_f16<<<dim3(512), NT, 0, stream>>>(Q, Kw, Vw, O);
}

// Round 8
// 96.120 us; speedup vs baseline: 3.7925x; 1.1291x over previous
//
#include <hip/hip_runtime.h>
#include <hip/hip_fp16.h>

typedef __attribute__((ext_vector_type(8))) _Float16 f16x8;
typedef __attribute__((ext_vector_type(4))) _Float16 f16x4;
typedef __attribute__((ext_vector_type(8))) unsigned short u16x8;
typedef __attribute__((ext_vector_type(4))) float f32x4;

constexpr int NT = 256;
constexpr int TILE_SHORTS = 4096;   // 64 rows x 64 fp16 = 8KB tile image

// phys 16B-chunk swizzle: row r, logical chunk c (0..7) -> short offset
__device__ __forceinline__ int swzoff(int row, int c) {
    return row * 64 + ((c ^ (row & 7)) << 3);
}
__device__ __forceinline__ unsigned short f2h_u(float x) {
    return __half_as_ushort(__float2half(x));
}

// direct global->LDS DMA, 16B per lane. LDS base must be WAVE-UNIFORM
// (hardware adds lane*16); global src is per-lane.
#define GLDS(gp, lp)                                                           \
    __builtin_amdgcn_global_load_lds(                                          \
        (const __attribute__((address_space(1))) void*)(const void*)(gp),      \
        (__attribute__((address_space(3))) void*)(void*)(lp), 16, 0, 0)

// ============ pre-pass: f32 -> fp16 swizzled tile images in ws ============
// (R0-exact version)
__global__ __launch_bounds__(256, 4) void prepass(
    const float* __restrict__ Kg, const float* __restrict__ Vg,
    unsigned short* __restrict__ Kw, unsigned short* __restrict__ Vw)
{
    __shared__ __align__(16) float Vl[64 * 68];
    const int tile = blockIdx.x;      // 0..31
    const int bh   = blockIdx.y;      // 0..15
    const int b = bh >> 3, h = bh & 7;
    const int tid = threadIdx.x;
    const size_t gbase = (((size_t)b * 2048 + tile * 64) * 8 + h) * 64;

    // stage V tile f32 into LDS (coalesced)
    #pragma unroll
    for (int j = 0; j < 4; ++j) {
        int id = j * 256 + tid, row = id >> 4, c4 = id & 15;
        *(float4*)&Vl[row * 68 + c4 * 4] =
            *(const float4*)&Vg[gbase + (size_t)row * 512 + c4 * 4];
    }

    // K image: row-major fp16, 16B chunks XOR-swizzled
    unsigned short* Ko = Kw + (size_t)(bh * 32 + tile) * TILE_SHORTS;
    #pragma unroll
    for (int j = 0; j < 2; ++j) {
        int id = j * 256 + tid, row = id >> 3, c = id & 7;
        const float* src = &Kg[gbase + (size_t)row * 512 + c * 8];
        float4 x = *(const float4*)src, y = *(const float4*)(src + 4);
        u16x8 o;
        o[0] = f2h_u(x.x); o[1] = f2h_u(x.y); o[2] = f2h_u(x.z); o[3] = f2h_u(x.w);
        o[4] = f2h_u(y.x); o[5] = f2h_u(y.y); o[6] = f2h_u(y.z); o[7] = f2h_u(y.w);
        *(u16x8*)&Ko[swzoff(row, c)] = o;
    }
    __syncthreads();

    // V^T image, k-permuted so one b128 = the 4 B-frags of 16x16x16 PV:
    // store at k' = quad*16 + c*4 + i the element k = c*16 + quad*4 + i
    unsigned short* Vo = Vw + (size_t)(bh * 32 + tile) * TILE_SHORTS;
    #pragma unroll
    for (int j = 0; j < 2; ++j) {
        int id = j * 256 + tid, vrow = id >> 3, g = id & 7;
        u16x8 o;
        #pragma unroll
        for (int jj = 0; jj < 8; ++jj) {
            int kk = ((g & 1) * 2 + (jj >> 2)) * 16 + (g >> 1) * 4 + (jj & 3);
            o[jj] = f2h_u(Vl[kk * 68 + vrow]);
        }
        *(u16x8*)&Vo[swzoff(vrow, g)] = o;
    }
}

// ============ main kernel: R0 structure + global_load_lds staging ============
// R7 retry with ONE change: an EXPLICIT `s_waitcnt vmcnt(0)` before each
// __syncthreads. R7's NaN is consistent with the compiler not draining the
// DMA's outstanding LDS writes at the barrier (it may model the intrinsic's
// LDS write imprecisely); the explicit drain sits exactly where the implicit
// one would, so it is free if redundant and correct if not.
__global__ __launch_bounds__(NT, 2) void attn_pow2_f16(
    const float* __restrict__ Qg,
    const unsigned short* __restrict__ Kw, const unsigned short* __restrict__ Vw,
    float* __restrict__ Og)
{
    __shared__ __align__(16) unsigned short lds[4 * TILE_SHORTS];  // 32 KiB
    unsigned short* const Kb = lds;                    // 2 buffers
    unsigned short* const Vb = lds + 2 * TILE_SHORTS;  // 2 buffers
    const int tid  = threadIdx.x;
    const int lane = tid & 63;
    const int wave = tid >> 6;
    const int a    = lane & 15;
    const int quad = lane >> 4;
    const int m0   = wave * 16;

    // heavy+light pairing swizzle (R0-exact, bijection over 512 blocks)
    int r0 = (int)blockIdx.x;
    int wr = (r0 < 256) ? r0 : (767 - r0);
    const int qt = 31 - (wr >> 4);
    const int bh = wr & 15;
    const int b = bh >> 3, h = bh & 7;
    const int q0 = qt * 64;

    // ---- Q B-frags from global f32: B[n=q=a][k=d=ks*32+quad*8+j] ----
    f16x8 bQ[2];
    {
        const size_t qrowbase = (((size_t)b * 2048 + q0 + m0 + a) * 8 + h) * 64;
        #pragma unroll
        for (int ks = 0; ks < 2; ++ks) {
            const float* src = &Qg[qrowbase + ks * 32 + quad * 8];
            float4 x = *(const float4*)src, y = *(const float4*)(src + 4);
            u16x8 o;
            o[0] = f2h_u(x.x); o[1] = f2h_u(x.y); o[2] = f2h_u(x.z); o[3] = f2h_u(x.w);
            o[4] = f2h_u(y.x); o[5] = f2h_u(y.y); o[6] = f2h_u(y.z); o[7] = f2h_u(y.w);
            bQ[ks] = __builtin_bit_cast(f16x8, o);
        }
    }

    const unsigned short* Ktiles = Kw + (size_t)bh * 32 * TILE_SHORTS;
    const unsigned short* Vtiles = Vw + (size_t)bh * 32 * TILE_SHORTS;

    // DMA-stage tile kt into buffer buf. Per wave: 2x1KB for K, 2x1KB for V.
    // LDS dest = wave-uniform base (HW adds lane*16); global src is per-lane.
    auto stage = [&](int buf, int kt) {
        const unsigned short* kg = Ktiles + (size_t)kt * TILE_SHORTS;
        const unsigned short* vg = Vtiles + (size_t)kt * TILE_SHORTS;
        unsigned short* kl = Kb + buf * TILE_SHORTS;
        unsigned short* vl = Vb + buf * TILE_SHORTS;
        #pragma unroll
        for (int j = 0; j < 2; ++j) {
            const int so = wave * 1024 + j * 512;     // shorts; wave-uniform
            GLDS(kg + so + lane * 8, kl + so);
            GLDS(vg + so + lane * 8, vl + so);
        }
    };

    f32x4 oacc[4];
    #pragma unroll
    for (int n = 0; n < 4; ++n) oacc[n] = (f32x4){0.f, 0.f, 0.f, 0.f};
    float den_l = 0.f;

    union U8 { u16x8 u; f16x4 q[2]; f16x8 f; };

    stage(0, 0);                       // prologue: first tile in flight

    for (int kt = 0; kt <= qt; ++kt) {
        const int buf = kt & 1;
        // EXPLICIT drain of this wave's outstanding DMA-to-LDS, then barrier.
        asm volatile("s_waitcnt vmcnt(0)" ::: "memory");
        __builtin_amdgcn_sched_barrier(0);
        __syncthreads();               // all waves drained -> buf complete;
                                       // also fences WAR for buf^1 re-stage
        if (kt < qt) stage(buf ^ 1, kt + 1);   // full compute phase of cover

        const unsigned short* Kc = Kb + buf * TILE_SHORTS;
        const unsigned short* Vc = Vb + buf * TILE_SHORTS;

        // ---- S^T = K·Q^T per 16-row k-strip: C-layout == A-layout of S ----
        f32x4 sacc[4];
        #pragma unroll
        for (int s = 0; s < 4; ++s) sacc[s] = (f32x4){0.f, 0.f, 0.f, 0.f};
        #pragma unroll
        for (int s = 0; s < 4; ++s) {
            #pragma unroll
            for (int ks = 0; ks < 2; ++ks) {
                U8 ak; ak.u = *(const u16x8*)&Kc[swzoff(s * 16 + a, ks * 4 + quad)];
                sacc[s] = __builtin_amdgcn_mfma_f32_16x16x32_f16(ak.f, bQ[ks], sacc[s], 0, 0, 0);
            }
        }

        // ---- square, mask (diag), den, convert in-register ----
        const bool diag = (kt == qt);
        f16x4 aS[4];
        #pragma unroll
        for (int s = 0; s < 4; ++s) {
            float p[4];
            #pragma unroll
            for (int r = 0; r < 4; ++r) {
                float d0 = sacc[s][r];
                float v = d0 * d0;
                if (diag && (s * 16 + quad * 4 + r) > (m0 + a)) v = 0.f;
                p[r] = v;
            }
            den_l += (p[0] + p[1]) + (p[2] + p[3]);
            aS[s] = (f16x4){(_Float16)p[0], (_Float16)p[1], (_Float16)p[2], (_Float16)p[3]};
        }

        // ---- PV: O += S·V via 16x16x16, S^T C-regs feed A directly ----
        #pragma unroll
        for (int n = 0; n < 4; ++n) {
            U8 va, vb;
            va.u = *(const u16x8*)&Vc[swzoff(n * 16 + a, quad * 2)];
            vb.u = *(const u16x8*)&Vc[swzoff(n * 16 + a, quad * 2 + 1)];
            oacc[n] = __builtin_amdgcn_mfma_f32_16x16x16f16(aS[0], va.q[0], oacc[n], 0, 0, 0);
            oacc[n] = __builtin_amdgcn_mfma_f32_16x16x16f16(aS[1], va.q[1], oacc[n], 0, 0, 0);
            oacc[n] = __builtin_amdgcn_mfma_f32_16x16x16f16(aS[2], vb.q[0], oacc[n], 0, 0, 0);
            oacc[n] = __builtin_amdgcn_mfma_f32_16x16x16f16(aS[3], vb.q[1], oacc[n], 0, 0, 0);
        }
    }

    // ---- den: reduce across quads (same q=a), then gather per output row ----
    den_l += __shfl_xor(den_l, 16);
    den_l += __shfl_xor(den_l, 32);

    float invz[4];
    #pragma unroll
    for (int r = 0; r < 4; ++r) {
        float dq = __shfl(den_l, quad * 4 + r);   // lane holding a == quad*4+r
        invz[r] = 1.0f / (dq + 1e-5f);
    }

    #pragma unroll
    for (int n = 0; n < 4; ++n) {
        #pragma unroll
        for (int r = 0; r < 4; ++r) {
            int t = q0 + m0 + quad * 4 + r;
            int v = n * 16 + a;
            Og[(((size_t)b * 2048 + t) * 8 + h) * 64 + v] = oacc[n][r] * invz[r];
        }
    }
}

extern "C" void kernel_launch(void* const* d_in, const int* in_sizes, int n_in,
                              void* d_out, int out_size, void* d_ws, size_t ws_size,
                              hipStream_t stream) {
    const float* Q = (const float*)d_in[0];
    const float* K = (const float*)d_in[1];
    const float* V = (const float*)d_in[2];
    float* O = (float*)d_out;
    unsigned short* Kw = (unsigned short*)d_ws;                 // 4 MB
    unsigned short* Vw = Kw + (size_t)16 * 32 * TILE_SHORTS;    // 4 MB

    prepass<<<dim3(32, 16), 256, 0, stream>>>(K, V, Kw, Vw);
    attn_pow2_f16<<<dim3(512), NT, 0, stream>>>(Q, Kw, Vw, O);
}

// Round 9
// 95.519 us; speedup vs baseline: 3.8164x; 1.0063x over previous
//
#include <hip/hip_runtime.h>
#include <hip/hip_fp16.h>

typedef __attribute__((ext_vector_type(8))) _Float16 f16x8;
typedef __attribute__((ext_vector_type(4))) _Float16 f16x4;
typedef __attribute__((ext_vector_type(8))) unsigned short u16x8;
typedef __attribute__((ext_vector_type(4))) float f32x4;

constexpr int NT = 256;
constexpr int TILE_SHORTS = 4096;   // 64 rows x 64 fp16 = 8KB tile image

// phys 16B-chunk swizzle: row r, logical chunk c (0..7) -> short offset
__device__ __forceinline__ int swzoff(int row, int c) {
    return row * 64 + ((c ^ (row & 7)) << 3);
}
__device__ __forceinline__ unsigned short f2h_u(float x) {
    return __half_as_ushort(__float2half(x));
}

// direct global->LDS DMA, 16B per lane. LDS base must be WAVE-UNIFORM
// (hardware adds lane*16); global src is per-lane.
#define GLDS(gp, lp)                                                           \
    __builtin_amdgcn_global_load_lds(                                          \
        (const __attribute__((address_space(1))) void*)(const void*)(gp),      \
        (__attribute__((address_space(3))) void*)(void*)(lp), 16, 0, 0)

// ============ pre-pass: f32 -> fp16 swizzled tile images in ws ============
// (R0-exact version)
__global__ __launch_bounds__(256, 4) void prepass(
    const float* __restrict__ Kg, const float* __restrict__ Vg,
    unsigned short* __restrict__ Kw, unsigned short* __restrict__ Vw)
{
    __shared__ __align__(16) float Vl[64 * 68];
    const int tile = blockIdx.x;      // 0..31
    const int bh   = blockIdx.y;      // 0..15
    const int b = bh >> 3, h = bh & 7;
    const int tid = threadIdx.x;
    const size_t gbase = (((size_t)b * 2048 + tile * 64) * 8 + h) * 64;

    // stage V tile f32 into LDS (coalesced)
    #pragma unroll
    for (int j = 0; j < 4; ++j) {
        int id = j * 256 + tid, row = id >> 4, c4 = id & 15;
        *(float4*)&Vl[row * 68 + c4 * 4] =
            *(const float4*)&Vg[gbase + (size_t)row * 512 + c4 * 4];
    }

    // K image: row-major fp16, 16B chunks XOR-swizzled
    unsigned short* Ko = Kw + (size_t)(bh * 32 + tile) * TILE_SHORTS;
    #pragma unroll
    for (int j = 0; j < 2; ++j) {
        int id = j * 256 + tid, row = id >> 3, c = id & 7;
        const float* src = &Kg[gbase + (size_t)row * 512 + c * 8];
        float4 x = *(const float4*)src, y = *(const float4*)(src + 4);
        u16x8 o;
        o[0] = f2h_u(x.x); o[1] = f2h_u(x.y); o[2] = f2h_u(x.z); o[3] = f2h_u(x.w);
        o[4] = f2h_u(y.x); o[5] = f2h_u(y.y); o[6] = f2h_u(y.z); o[7] = f2h_u(y.w);
        *(u16x8*)&Ko[swzoff(row, c)] = o;
    }
    __syncthreads();

    // V^T image, k-permuted so one b128 = the 4 B-frags of 16x16x16 PV:
    // store at k' = quad*16 + c*4 + i the element k = c*16 + quad*4 + i
    unsigned short* Vo = Vw + (size_t)(bh * 32 + tile) * TILE_SHORTS;
    #pragma unroll
    for (int j = 0; j < 2; ++j) {
        int id = j * 256 + tid, vrow = id >> 3, g = id & 7;
        u16x8 o;
        #pragma unroll
        for (int jj = 0; jj < 8; ++jj) {
            int kk = ((g & 1) * 2 + (jj >> 2)) * 16 + (g >> 1) * 4 + (jj & 3);
            o[jj] = f2h_u(Vl[kk * 68 + vrow]);
        }
        *(u16x8*)&Vo[swzoff(vrow, g)] = o;
    }
}

// ====== main kernel: R8 structure, TWO KV-tiles per sync event (KVBLK=128) ==
// The per-iteration fixed cost (vmcnt drain + barrier + wave restart) is the
// dominant unexplained interior term; halving the number of sync events by
// processing 2 tiles per pipeline step attacks it directly. LDS = 64 KiB
// (2 bufs x 2 tiles x (K+V)) -> still 2 blocks/CU. Everything else R8-exact.
__global__ __launch_bounds__(NT, 2) void attn_pow2_f16(
    const float* __restrict__ Qg,
    const unsigned short* __restrict__ Kw, const unsigned short* __restrict__ Vw,
    float* __restrict__ Og)
{
    __shared__ __align__(16) unsigned short lds[8 * TILE_SHORTS];  // 64 KiB
    unsigned short* const Kb = lds;                     // [buf*2+slot] tiles
    unsigned short* const Vb = lds + 4 * TILE_SHORTS;   // [buf*2+slot] tiles
    const int tid  = threadIdx.x;
    const int lane = tid & 63;
    const int wave = tid >> 6;
    const int a    = lane & 15;
    const int quad = lane >> 4;
    const int m0   = wave * 16;

    // heavy+light pairing swizzle (R0-exact, bijection over 512 blocks)
    int r0 = (int)blockIdx.x;
    int wr = (r0 < 256) ? r0 : (767 - r0);
    const int qt = 31 - (wr >> 4);
    const int bh = wr & 15;
    const int b = bh >> 3, h = bh & 7;
    const int q0 = qt * 64;

    // ---- Q B-frags from global f32: B[n=q=a][k=d=ks*32+quad*8+j] ----
    f16x8 bQ[2];
    {
        const size_t qrowbase = (((size_t)b * 2048 + q0 + m0 + a) * 8 + h) * 64;
        #pragma unroll
        for (int ks = 0; ks < 2; ++ks) {
            const float* src = &Qg[qrowbase + ks * 32 + quad * 8];
            float4 x = *(const float4*)src, y = *(const float4*)(src + 4);
            u16x8 o;
            o[0] = f2h_u(x.x); o[1] = f2h_u(x.y); o[2] = f2h_u(x.z); o[3] = f2h_u(x.w);
            o[4] = f2h_u(y.x); o[5] = f2h_u(y.y); o[6] = f2h_u(y.z); o[7] = f2h_u(y.w);
            bQ[ks] = __builtin_bit_cast(f16x8, o);
        }
    }

    const unsigned short* Ktiles = Kw + (size_t)bh * 32 * TILE_SHORTS;
    const unsigned short* Vtiles = Vw + (size_t)bh * 32 * TILE_SHORTS;

    // DMA-stage tiles t0,t0+1 (clamped) into slots 0,1 of buffer buf.
    // 8 GLDS per wave per step; LDS dest wave-uniform, global src per-lane.
    auto stage = [&](int buf, int t0) {
        #pragma unroll
        for (int s2 = 0; s2 < 2; ++s2) {
            int t = t0 + s2; if (t > 31) t = 31;   // clamp: harmless data
            const unsigned short* kg = Ktiles + (size_t)t * TILE_SHORTS;
            const unsigned short* vg = Vtiles + (size_t)t * TILE_SHORTS;
            unsigned short* kl = Kb + (size_t)(buf * 2 + s2) * TILE_SHORTS;
            unsigned short* vl = Vb + (size_t)(buf * 2 + s2) * TILE_SHORTS;
            #pragma unroll
            for (int j = 0; j < 2; ++j) {
                const int so = wave * 1024 + j * 512;     // shorts; wave-uniform
                GLDS(kg + so + lane * 8, kl + so);
                GLDS(vg + so + lane * 8, vl + so);
            }
        }
    };

    f32x4 oacc[4];
    #pragma unroll
    for (int n = 0; n < 4; ++n) oacc[n] = (f32x4){0.f, 0.f, 0.f, 0.f};
    float den_l = 0.f;

    union U8 { u16x8 u; f16x4 q[2]; f16x8 f; };

    auto compute = [&](const unsigned short* Kc, const unsigned short* Vc,
                       bool diag) {
        // ---- S^T = K·Q^T per 16-row k-strip: C-layout == A-layout of S ----
        f32x4 sacc[4];
        #pragma unroll
        for (int s = 0; s < 4; ++s) sacc[s] = (f32x4){0.f, 0.f, 0.f, 0.f};
        #pragma unroll
        for (int s = 0; s < 4; ++s) {
            #pragma unroll
            for (int ks = 0; ks < 2; ++ks) {
                U8 ak; ak.u = *(const u16x8*)&Kc[swzoff(s * 16 + a, ks * 4 + quad)];
                sacc[s] = __builtin_amdgcn_mfma_f32_16x16x32_f16(ak.f, bQ[ks], sacc[s], 0, 0, 0);
            }
        }

        // ---- square, mask (diag), den, convert in-register ----
        f16x4 aS[4];
        #pragma unroll
        for (int s = 0; s < 4; ++s) {
            float p[4];
            #pragma unroll
            for (int r = 0; r < 4; ++r) {
                float d0 = sacc[s][r];
                float v = d0 * d0;
                if (diag && (s * 16 + quad * 4 + r) > (m0 + a)) v = 0.f;
                p[r] = v;
            }
            den_l += (p[0] + p[1]) + (p[2] + p[3]);
            aS[s] = (f16x4){(_Float16)p[0], (_Float16)p[1], (_Float16)p[2], (_Float16)p[3]};
        }

        // ---- PV: O += S·V via 16x16x16, S^T C-regs feed A directly ----
        #pragma unroll
        for (int n = 0; n < 4; ++n) {
            U8 va, vb;
            va.u = *(const u16x8*)&Vc[swzoff(n * 16 + a, quad * 2)];
            vb.u = *(const u16x8*)&Vc[swzoff(n * 16 + a, quad * 2 + 1)];
            oacc[n] = __builtin_amdgcn_mfma_f32_16x16x16f16(aS[0], va.q[0], oacc[n], 0, 0, 0);
            oacc[n] = __builtin_amdgcn_mfma_f32_16x16x16f16(aS[1], va.q[1], oacc[n], 0, 0, 0);
            oacc[n] = __builtin_amdgcn_mfma_f32_16x16x16f16(aS[2], vb.q[0], oacc[n], 0, 0, 0);
            oacc[n] = __builtin_amdgcn_mfma_f32_16x16x16f16(aS[3], vb.q[1], oacc[n], 0, 0, 0);
        }
    };

    stage(0, 0);                       // prologue: first tile-pair in flight

    for (int t0 = 0; t0 <= qt; t0 += 2) {
        const int buf = (t0 >> 1) & 1;
        // EXPLICIT drain of this wave's outstanding DMA-to-LDS (required:
        // __syncthreads alone does NOT cover global_load_lds — R7 lesson),
        // then barrier. One sync event per TWO tiles.
        asm volatile("s_waitcnt vmcnt(0)" ::: "memory");
        __builtin_amdgcn_sched_barrier(0);
        __syncthreads();               // pair complete; WAR for buf^1 re-stage
        if (t0 + 2 <= qt) stage(buf ^ 1, t0 + 2);   // 2-tile compute of cover

        compute(Kb + (size_t)(buf * 2 + 0) * TILE_SHORTS,
                Vb + (size_t)(buf * 2 + 0) * TILE_SHORTS, t0 == qt);
        if (t0 + 1 <= qt)
            compute(Kb + (size_t)(buf * 2 + 1) * TILE_SHORTS,
                    Vb + (size_t)(buf * 2 + 1) * TILE_SHORTS, t0 + 1 == qt);
    }

    // ---- den: reduce across quads (same q=a), then gather per output row ----
    den_l += __shfl_xor(den_l, 16);
    den_l += __shfl_xor(den_l, 32);

    float invz[4];
    #pragma unroll
    for (int r = 0; r < 4; ++r) {
        float dq = __shfl(den_l, quad * 4 + r);   // lane holding a == quad*4+r
        invz[r] = 1.0f / (dq + 1e-5f);
    }

    #pragma unroll
    for (int n = 0; n < 4; ++n) {
        #pragma unroll
        for (int r = 0; r < 4; ++r) {
            int t = q0 + m0 + quad * 4 + r;
            int v = n * 16 + a;
            Og[(((size_t)b * 2048 + t) * 8 + h) * 64 + v] = oacc[n][r] * invz[r];
        }
    }
}

extern "C" void kernel_launch(void* const* d_in, const int* in_sizes, int n_in,
                              void* d_out, int out_size, void* d_ws, size_t ws_size,
                              hipStream_t stream) {
    const float* Q = (const float*)d_in[0];
    const float* K = (const float*)d_in[1];
    const float* V = (const float*)d_in[2];
    float* O = (float*)d_out;
    unsigned short* Kw = (unsigned short*)d_ws;                 // 4 MB
    unsigned short* Vw = Kw + (size_t)16 * 32 * TILE_SHORTS;    // 4 MB

    prepass<<<dim3(32, 16), 256, 0, stream>>>(K, V, Kw, Vw);
    attn_pow2_f16<<<dim3(512), NT, 0, stream>>>(Q, Kw, Vw, O);
}